// Round 3
// baseline (680.998 us; speedup 1.0000x reference)
//
#include <hip/hip_runtime.h>

typedef __attribute__((ext_vector_type(8))) short bf16x8;
typedef __attribute__((ext_vector_type(4))) float f32x4;

#define M_TOT 8192
#define N_TOT 8192
#define K_TOT 256

// ---------- helpers ----------
__device__ __forceinline__ unsigned short f2bf(float f) {
  unsigned u = __float_as_uint(f);
  unsigned r = (u + 0x7FFFu + ((u >> 16) & 1u)) >> 16;  // RNE, no NaN in data
  return (unsigned short)r;
}
__device__ __forceinline__ float bf2f(unsigned short h) {
  return __uint_as_float(((unsigned)h) << 16);
}
__device__ __forceinline__ unsigned long long shfl_xor_u64(unsigned long long v, int m) {
  unsigned lo = (unsigned)v, hi = (unsigned)(v >> 32);
  lo = __shfl_xor(lo, m, 64);
  hi = __shfl_xor(hi, m, 64);
  return (((unsigned long long)hi) << 32) | lo;
}
__device__ __forceinline__ void load_lds16(const void* g, void* l) {
  __builtin_amdgcn_global_load_lds(
      (const __attribute__((address_space(1))) unsigned int*)g,
      (__attribute__((address_space(3))) unsigned int*)l, 16, 0, 0);
}

// ---------- prep X: split-2 + init keys ----------
__global__ __launch_bounds__(256) void prep_x_kernel(const float* __restrict__ in,
                                                     unsigned short* __restrict__ s0,
                                                     unsigned short* __restrict__ s1,
                                                     unsigned long long* __restrict__ keys) {
  const int t = blockIdx.x * 256 + threadIdx.x;
  if (blockIdx.x < 32) keys[t] = ~0ULL;  // 8192 keys
  float4 v = reinterpret_cast<const float4*>(in)[t];
  float f[4] = {v.x, v.y, v.z, v.w};
  unsigned short a0[4], a1[4];
#pragma unroll
  for (int c = 0; c < 4; ++c) {
    unsigned short b0 = f2bf(f[c]);
    a0[c] = b0;
    a1[c] = f2bf(f[c] - bf2f(b0));  // residual exact
  }
  ushort4 o0 = {a0[0], a0[1], a0[2], a0[3]};
  ushort4 o1 = {a1[0], a1[1], a1[2], a1[3]};
  reinterpret_cast<ushort4*>(s0)[t] = o0;
  reinterpret_cast<ushort4*>(s1)[t] = o1;
}

// ---------- prep E: split-2 + fp32 ||e||^2 (wave per row) ----------
__global__ __launch_bounds__(256) void prep_e_kernel(const float* __restrict__ in,
                                                     unsigned short* __restrict__ s0,
                                                     unsigned short* __restrict__ s1,
                                                     float* __restrict__ esq) {
  const int t = blockIdx.x * 256 + threadIdx.x;
  const int lane = threadIdx.x & 63;
  float4 v = reinterpret_cast<const float4*>(in)[t];
  float f[4] = {v.x, v.y, v.z, v.w};
  unsigned short a0[4], a1[4];
#pragma unroll
  for (int c = 0; c < 4; ++c) {
    unsigned short b0 = f2bf(f[c]);
    a0[c] = b0;
    a1[c] = f2bf(f[c] - bf2f(b0));
  }
  ushort4 o0 = {a0[0], a0[1], a0[2], a0[3]};
  ushort4 o1 = {a1[0], a1[1], a1[2], a1[3]};
  reinterpret_cast<ushort4*>(s0)[t] = o0;
  reinterpret_cast<ushort4*>(s1)[t] = o1;
  float s = f[0] * f[0] + f[1] * f[1] + f[2] * f[2] + f[3] * f[3];
#pragma unroll
  for (int off = 32; off > 0; off >>= 1) s += __shfl_xor(s, off, 64);
  if (lane == 0) esq[blockIdx.x * 4 + (threadIdx.x >> 6)] = s;  // wave == row
}

// ---------- fused split-2 bf16 MFMA dist-GEMM + argmin ----------
// 128x128 tile, 4 waves 2x2, each wave 4x4 MFMA tiles of 16x16x32.
// 3 split-passes: x0e0, x0e1, x1e0  (error <= ~3e-4 abs on dist2, gap ~O(1)).
// LDS 32 KB: A0,A1,B0,B1 x [8 segs x 512 ushorts]; global_load_lds(16B) with
// inverse-swizzled source addressing -> ds_read_b128 frag reads 2-way (free).
__global__ __launch_bounds__(256, 5) void mfma_argmin_kernel(
    const unsigned short* __restrict__ X0, const unsigned short* __restrict__ X1,
    const unsigned short* __restrict__ E0, const unsigned short* __restrict__ E1,
    const float* __restrict__ esq, unsigned long long* __restrict__ keys) {
  __shared__ unsigned short lds[16384];  // 32 KB

  const int tid = threadIdx.x;
  const int wid = tid >> 6;
  const int lane = tid & 63;
  const int li = lane & 15, lq = lane >> 4;

  // XCD-sharded N: blocks with same (bid&7) share an E-slice (L2-resident)
  const int bid = blockIdx.x;
  const int nb = (bid & 7) * 8 + ((bid >> 3) & 7);
  const int mb = bid >> 6;
  const int m0 = mb * 128, n0 = nb * 128;
  const int wm = (wid >> 1) * 64, wn = (wid & 1) * 64;

  // staging: lane -> (row-in-segment, k-part) inverse swizzle
  const int r_st = lane >> 2;
  const int kp_st = ((lane & 3) - (r_st >> 1)) & 3;
  // frag read: swizzled byte offset within a 1024B segment
  const int sw = (li * 4 + ((lq + (li >> 1)) & 3)) * 16;

  const unsigned short* __restrict__ srcs[4] = {X0, X1, E0, E1};

  f32x4 acc[4][4];
#pragma unroll
  for (int a = 0; a < 4; ++a)
#pragma unroll
    for (int b = 0; b < 4; ++b) acc[a][b] = (f32x4){0.f, 0.f, 0.f, 0.f};

  for (int kc = 0; kc < 8; ++kc) {
    const int k0 = kc * 32;
    __syncthreads();
#pragma unroll
    for (int j = 0; j < 8; ++j) {
      const int tt = j * 4 + wid;      // 32 segment-loads over 4 waves
      const int tsel = tt >> 3;        // 0=X0 1=X1 2=E0 3=E1
      const int seg = tt & 7;
      const int rowbase = ((tsel >= 2) ? n0 : m0) + seg * 16 + r_st;
      const unsigned short* gp = srcs[tsel] + (size_t)rowbase * K_TOT + k0 + kp_st * 8;
      unsigned short* lp = &lds[tsel * 4096 + seg * 512];
      load_lds16(gp, lp);
    }
    __syncthreads();

    bf16x8 afr[2][4];
#pragma unroll
    for (int s = 0; s < 2; ++s)
#pragma unroll
      for (int mi = 0; mi < 4; ++mi)
        afr[s][mi] = *(const bf16x8*)((const char*)lds + s * 8192 +
                                      ((wm >> 4) + mi) * 1024 + sw);

#pragma unroll
    for (int ni = 0; ni < 4; ++ni) {
      const char* bbase = (const char*)lds + 16384 + ((wn >> 4) + ni) * 1024 + sw;
      bf16x8 b0 = *(const bf16x8*)(bbase);
      bf16x8 b1 = *(const bf16x8*)(bbase + 8192);
#pragma unroll
      for (int mi = 0; mi < 4; ++mi) {
        f32x4 c = acc[mi][ni];
        c = __builtin_amdgcn_mfma_f32_16x16x32_bf16(afr[0][mi], b0, c, 0, 0, 0);
        c = __builtin_amdgcn_mfma_f32_16x16x32_bf16(afr[0][mi], b1, c, 0, 0, 0);
        c = __builtin_amdgcn_mfma_f32_16x16x32_bf16(afr[1][mi], b0, c, 0, 0, 0);
        acc[mi][ni] = c;
      }
    }
  }

  // ---- argmin epilogue: dist = ||e||^2 - 2 x.e ----
  // C/D layout: n = lane&15 (+ni*16), m = (lane>>4)*4 + reg (+mi*16)
  const int nbase = n0 + wn + li;
  float ev[4];
#pragma unroll
  for (int ni = 0; ni < 4; ++ni) ev[ni] = esq[nbase + ni * 16];

#pragma unroll
  for (int mi = 0; mi < 4; ++mi) {
#pragma unroll
    for (int r = 0; r < 4; ++r) {
      unsigned long long best = ~0ULL;
#pragma unroll
      for (int ni = 0; ni < 4; ++ni) {
        float d = fmaxf(ev[ni] - 2.0f * acc[mi][ni][r], 0.0f);  // >=0 -> bits order-preserving
        unsigned long long key =
            (((unsigned long long)__float_as_uint(d)) << 32) | (unsigned)(nbase + ni * 16);
        best = key < best ? key : best;
      }
#pragma unroll
      for (int off = 1; off < 16; off <<= 1) {
        unsigned long long o = shfl_xor_u64(best, off);
        best = o < best ? o : best;
      }
      if (li == 0) {
        const int m = m0 + wm + mi * 16 + lq * 4 + r;
        atomicMin(&keys[m], best);  // tie -> lower idx = first occurrence
      }
    }
  }
}

// ---------- gather + index write (4 rows per block) ----------
__global__ __launch_bounds__(256) void gather2_kernel(const float* __restrict__ embed,
                                                      const unsigned long long* __restrict__ keys,
                                                      float* __restrict__ out) {
  const int row = blockIdx.x * 4 + (threadIdx.x >> 6);
  const int lane = threadIdx.x & 63;
  const unsigned idx = (unsigned)keys[row];
  reinterpret_cast<float4*>(out)[(size_t)row * 64 + lane] =
      reinterpret_cast<const float4*>(embed)[(size_t)idx * 64 + lane];
  if (lane == 0) out[(size_t)M_TOT * K_TOT + row] = (float)idx;
}

// ================= fallback (round-1 fp32 path, known-correct) =================
#define BM 32
#define BN 64
#define KC 32
#define NQ 2
#define NPQ (N_TOT / NQ)
#define SB 72

__global__ __launch_bounds__(256) void esq_kernel(const float* __restrict__ embed,
                                                  float* __restrict__ esq) {
  const int lane = threadIdx.x & 63;
  const int wave = threadIdx.x >> 6;
  const int code = blockIdx.x * 4 + wave;
  float4 v = reinterpret_cast<const float4*>(embed + (size_t)code * K_TOT)[lane];
  float s = v.x * v.x + v.y * v.y + v.z * v.z + v.w * v.w;
#pragma unroll
  for (int off = 32; off > 0; off >>= 1) s += __shfl_xor(s, off, 64);
  if (lane == 0) esq[code] = s;
}

__global__ __launch_bounds__(256, 2) void argmin_kernel(
    const float* __restrict__ x, const float* __restrict__ embed,
    const float* __restrict__ esq, float* __restrict__ pval, int* __restrict__ pidx) {
  __shared__ float A[K_TOT][BM];
  __shared__ float Bs[KC][SB];
  const int tid = threadIdx.x;
  const int tx = tid & 15;
  const int ty = tid >> 4;
  const int q = blockIdx.x & 1;
  const int mb = blockIdx.x >> 1;
  const int m0 = mb * BM;
  const int nq0 = q * NPQ;
#pragma unroll
  for (int it = 0; it < 8; ++it) {
    int idx = it * 256 + tid;
    int row = idx >> 6;
    int k4 = idx & 63;
    float4 v = reinterpret_cast<const float4*>(x + (size_t)(m0 + row) * K_TOT)[k4];
    A[k4 * 4 + 0][row] = v.x; A[k4 * 4 + 1][row] = v.y;
    A[k4 * 4 + 2][row] = v.z; A[k4 * 4 + 3][row] = v.w;
  }
  float minv[2]; int mini[2];
#pragma unroll
  for (int r = 0; r < 2; ++r) { minv[r] = 3.4e38f; mini[r] = 0; }
  for (int ns = 0; ns < NPQ / BN; ++ns) {
    const int n0 = nq0 + ns * BN;
    float acc[2][4];
#pragma unroll
    for (int r = 0; r < 2; ++r)
#pragma unroll
      for (int c = 0; c < 4; ++c) acc[r][c] = 0.0f;
    for (int kc = 0; kc < K_TOT / KC; ++kc) {
      const int k0 = kc * KC;
      __syncthreads();
#pragma unroll
      for (int it = 0; it < 2; ++it) {
        int idx = it * 256 + tid;
        int nl = idx >> 3;
        int k4 = idx & 7;
        float4 v = reinterpret_cast<const float4*>(embed + (size_t)(n0 + nl) * K_TOT + k0)[k4];
        Bs[k4 * 4 + 0][nl] = v.x; Bs[k4 * 4 + 1][nl] = v.y;
        Bs[k4 * 4 + 2][nl] = v.z; Bs[k4 * 4 + 3][nl] = v.w;
      }
      __syncthreads();
#pragma unroll
      for (int kk = 0; kk < KC; ++kk) {
        float2 a = *reinterpret_cast<const float2*>(&A[k0 + kk][ty * 2]);
        float4 b = *reinterpret_cast<const float4*>(&Bs[kk][tx * 4]);
        acc[0][0] += a.x * b.x; acc[0][1] += a.x * b.y;
        acc[0][2] += a.x * b.z; acc[0][3] += a.x * b.w;
        acc[1][0] += a.y * b.x; acc[1][1] += a.y * b.y;
        acc[1][2] += a.y * b.z; acc[1][3] += a.y * b.w;
      }
    }
    float4 es = *reinterpret_cast<const float4*>(&esq[n0 + tx * 4]);
    float e[4] = {es.x, es.y, es.z, es.w};
#pragma unroll
    for (int r = 0; r < 2; ++r)
#pragma unroll
      for (int c = 0; c < 4; ++c) {
        float d = e[c] - 2.0f * acc[r][c];
        int id = n0 + tx * 4 + c;
        if (d < minv[r]) { minv[r] = d; mini[r] = id; }
      }
  }
#pragma unroll
  for (int r = 0; r < 2; ++r) {
    float v = minv[r]; int i = mini[r];
#pragma unroll
    for (int off = 1; off < 16; off <<= 1) {
      float vo = __shfl_xor(v, off, 64);
      int io = __shfl_xor(i, off, 64);
      if (vo < v || (vo == v && io < i)) { v = vo; i = io; }
    }
    if (tx == 0) {
      int row = m0 + ty * 2 + r;
      pval[q * M_TOT + row] = v;
      pidx[q * M_TOT + row] = i;
    }
  }
}

__global__ __launch_bounds__(256) void gather_kernel(
    const float* __restrict__ embed, const float* __restrict__ pval,
    const int* __restrict__ pidx, float* __restrict__ out) {
  const int row = blockIdx.x;
  float bv = pval[row]; int bi = pidx[row];
#pragma unroll
  for (int qq = 1; qq < NQ; ++qq) {
    float v = pval[qq * M_TOT + row];
    int i = pidx[qq * M_TOT + row];
    if (v < bv || (v == bv && i < bi)) { bv = v; bi = i; }
  }
  out[(size_t)row * K_TOT + threadIdx.x] = embed[(size_t)bi * K_TOT + threadIdx.x];
  if (threadIdx.x == 0) out[(size_t)M_TOT * K_TOT + row] = (float)bi;
}

// ================= launch =================
extern "C" void kernel_launch(void* const* d_in, const int* in_sizes, int n_in,
                              void* d_out, int out_size, void* d_ws, size_t ws_size,
                              hipStream_t stream) {
  const float* x = (const float*)d_in[0];
  const float* embed = (const float*)d_in[1];
  float* out = (float*)d_out;
  char* ws = (char*)d_ws;

  const size_t SPLIT_BYTES = (size_t)M_TOT * K_TOT * 2;  // 4 MB per split matrix
  const size_t need = (1u << 20) + 4 * SPLIT_BYTES;      // ~17.8 MB

  if (ws_size >= need) {
    unsigned long long* keys = (unsigned long long*)ws;  // 64 KB
    float* esq = (float*)(ws + 65536);                   // 32 KB
    unsigned short* S[4];
    for (int i = 0; i < 4; ++i) S[i] = (unsigned short*)(ws + (1u << 20) + i * SPLIT_BYTES);
    prep_x_kernel<<<2048, 256, 0, stream>>>(x, S[0], S[1], keys);
    prep_e_kernel<<<2048, 256, 0, stream>>>(embed, S[2], S[3], esq);
    mfma_argmin_kernel<<<4096, 256, 0, stream>>>(S[0], S[1], S[2], S[3], esq, keys);
    gather2_kernel<<<2048, 256, 0, stream>>>(embed, keys, out);
  } else {
    float* esq = (float*)ws;
    float* pval = (float*)(ws + 32768);
    int* pidx = (int*)(ws + 32768 + NQ * 32768);
    esq_kernel<<<2048, 256, 0, stream>>>(embed, esq);
    argmin_kernel<<<512, 256, 0, stream>>>(x, embed, esq, pval, pidx);
    gather_kernel<<<M_TOT, 256, 0, stream>>>(embed, pval, pidx, out);
  }
}

// Round 4
// 195.114 us; speedup vs baseline: 3.4903x; 3.4903x over previous
//
#include <hip/hip_runtime.h>

typedef __attribute__((ext_vector_type(8))) short bf16x8;
typedef __attribute__((ext_vector_type(4))) float f32x4;

#define M_TOT 8192
#define N_TOT 8192
#define K_TOT 256

// ---------- helpers ----------
__device__ __forceinline__ unsigned short f2bf(float f) {
  unsigned u = __float_as_uint(f);
  unsigned r = (u + 0x7FFFu + ((u >> 16) & 1u)) >> 16;  // RNE, no NaN in data
  return (unsigned short)r;
}
__device__ __forceinline__ float bf2f(unsigned short h) {
  return __uint_as_float(((unsigned)h) << 16);
}
__device__ __forceinline__ unsigned long long shfl_xor_u64(unsigned long long v, int m) {
  unsigned lo = (unsigned)v, hi = (unsigned)(v >> 32);
  lo = __shfl_xor(lo, m, 64);
  hi = __shfl_xor(hi, m, 64);
  return (((unsigned long long)hi) << 32) | lo;
}
__device__ __forceinline__ void load_lds16(const void* g, void* l) {
  __builtin_amdgcn_global_load_lds(
      (const __attribute__((address_space(1))) unsigned int*)g,
      (__attribute__((address_space(3))) unsigned int*)l, 16, 0, 0);
}

// ---------- fused prep: split-2 of x AND embed, + ||e||^2, + key init ----------
// grid 4096: blocks 0..2047 handle x (and blocks 0..31 init keys),
//            blocks 2048..4095 handle embed (+ per-wave esq).
__global__ __launch_bounds__(256) void prep_kernel(
    const float* __restrict__ x, const float* __restrict__ embed,
    unsigned short* __restrict__ X0, unsigned short* __restrict__ X1,
    unsigned short* __restrict__ E0, unsigned short* __restrict__ E1,
    float* __restrict__ esq, unsigned long long* __restrict__ keys) {
  const int bid = blockIdx.x;
  const bool is_e = bid >= 2048;
  const int lb = is_e ? bid - 2048 : bid;
  const int t = lb * 256 + threadIdx.x;
  if (bid < 32) keys[t] = ~0ULL;  // 8192 keys

  const float* __restrict__ in = is_e ? embed : x;
  unsigned short* __restrict__ s0 = is_e ? E0 : X0;
  unsigned short* __restrict__ s1 = is_e ? E1 : X1;

  float4 v = reinterpret_cast<const float4*>(in)[t];
  float f[4] = {v.x, v.y, v.z, v.w};
  unsigned short a0[4], a1[4];
#pragma unroll
  for (int c = 0; c < 4; ++c) {
    unsigned short b0 = f2bf(f[c]);
    a0[c] = b0;
    a1[c] = f2bf(f[c] - bf2f(b0));  // residual exact
  }
  ushort4 o0 = {a0[0], a0[1], a0[2], a0[3]};
  ushort4 o1 = {a1[0], a1[1], a1[2], a1[3]};
  reinterpret_cast<ushort4*>(s0)[t] = o0;
  reinterpret_cast<ushort4*>(s1)[t] = o1;

  if (is_e) {
    const int lane = threadIdx.x & 63;
    float s = f[0] * f[0] + f[1] * f[1] + f[2] * f[2] + f[3] * f[3];
#pragma unroll
    for (int off = 32; off > 0; off >>= 1) s += __shfl_xor(s, off, 64);
    if (lane == 0) esq[lb * 4 + (threadIdx.x >> 6)] = s;  // wave == e-row
  }
}

// ---------- fused split-2 bf16 MFMA dist-GEMM + argmin ----------
// 128x128 tile, 4 waves 2x2, each wave 4x4 MFMA tiles of 16x16x32.
// 3 split-passes: x0e0, x0e1, x1e0  (error <= ~3e-4 abs on dist2, gap ~O(1)).
// LDS 32 KB: A0,A1,B0,B1 x [8 segs x 512 ushorts]; global_load_lds(16B) with
// inverse-swizzled source addressing -> ds_read_b128 frag reads 2-way (free).
// launch_bounds (256,3): reg cap 170 — acc (64 AGPR) + ~84 VGPR fits with NO
// spill. (256,5) capped at ~102 and spilled accumulators -> 2.9 GB scratch
// traffic -> 3.3x regression (round-3 lesson).
__global__ __launch_bounds__(256, 3) void mfma_argmin_kernel(
    const unsigned short* __restrict__ X0, const unsigned short* __restrict__ X1,
    const unsigned short* __restrict__ E0, const unsigned short* __restrict__ E1,
    const float* __restrict__ esq, unsigned long long* __restrict__ keys) {
  __shared__ unsigned short lds[16384];  // 32 KB

  const int tid = threadIdx.x;
  const int wid = tid >> 6;
  const int lane = tid & 63;
  const int li = lane & 15, lq = lane >> 4;

  // XCD-sharded N: blocks with same (bid&7) share an E-slice (L2-resident)
  const int bid = blockIdx.x;
  const int nb = (bid & 7) * 8 + ((bid >> 3) & 7);
  const int mb = bid >> 6;
  const int m0 = mb * 128, n0 = nb * 128;
  const int wm = (wid >> 1) * 64, wn = (wid & 1) * 64;

  // staging: lane -> (row-in-segment, k-part) inverse swizzle
  const int r_st = lane >> 2;
  const int kp_st = ((lane & 3) - (r_st >> 1)) & 3;
  // frag read: swizzled byte offset within a 1024B segment
  const int sw = (li * 4 + ((lq + (li >> 1)) & 3)) * 16;

  const unsigned short* __restrict__ srcs[4] = {X0, X1, E0, E1};

  f32x4 acc[4][4];
#pragma unroll
  for (int a = 0; a < 4; ++a)
#pragma unroll
    for (int b = 0; b < 4; ++b) acc[a][b] = (f32x4){0.f, 0.f, 0.f, 0.f};

  for (int kc = 0; kc < 8; ++kc) {
    const int k0 = kc * 32;
    __syncthreads();
#pragma unroll
    for (int j = 0; j < 8; ++j) {
      const int tt = j * 4 + wid;      // 32 segment-loads over 4 waves
      const int tsel = tt >> 3;        // 0=X0 1=X1 2=E0 3=E1
      const int seg = tt & 7;
      const int rowbase = ((tsel >= 2) ? n0 : m0) + seg * 16 + r_st;
      const unsigned short* gp = srcs[tsel] + (size_t)rowbase * K_TOT + k0 + kp_st * 8;
      unsigned short* lp = &lds[tsel * 4096 + seg * 512];
      load_lds16(gp, lp);
    }
    __syncthreads();

    bf16x8 afr[2][4];
#pragma unroll
    for (int s = 0; s < 2; ++s)
#pragma unroll
      for (int mi = 0; mi < 4; ++mi)
        afr[s][mi] = *(const bf16x8*)((const char*)lds + s * 8192 +
                                      ((wm >> 4) + mi) * 1024 + sw);

#pragma unroll
    for (int ni = 0; ni < 4; ++ni) {
      const char* bbase = (const char*)lds + 16384 + ((wn >> 4) + ni) * 1024 + sw;
      bf16x8 b0 = *(const bf16x8*)(bbase);
      bf16x8 b1 = *(const bf16x8*)(bbase + 8192);
#pragma unroll
      for (int mi = 0; mi < 4; ++mi) {
        f32x4 c = acc[mi][ni];
        c = __builtin_amdgcn_mfma_f32_16x16x32_bf16(afr[0][mi], b0, c, 0, 0, 0);
        c = __builtin_amdgcn_mfma_f32_16x16x32_bf16(afr[0][mi], b1, c, 0, 0, 0);
        c = __builtin_amdgcn_mfma_f32_16x16x32_bf16(afr[1][mi], b0, c, 0, 0, 0);
        acc[mi][ni] = c;
      }
    }
  }

  // ---- argmin epilogue: dist = ||e||^2 - 2 x.e ----
  // C/D layout: n = lane&15 (+ni*16), m = (lane>>4)*4 + reg (+mi*16)
  const int nbase = n0 + wn + li;
  float ev[4];
#pragma unroll
  for (int ni = 0; ni < 4; ++ni) ev[ni] = esq[nbase + ni * 16];

#pragma unroll
  for (int mi = 0; mi < 4; ++mi) {
#pragma unroll
    for (int r = 0; r < 4; ++r) {
      unsigned long long best = ~0ULL;
#pragma unroll
      for (int ni = 0; ni < 4; ++ni) {
        float d = fmaxf(ev[ni] - 2.0f * acc[mi][ni][r], 0.0f);  // >=0 -> bits order-preserving
        unsigned long long key =
            (((unsigned long long)__float_as_uint(d)) << 32) | (unsigned)(nbase + ni * 16);
        best = key < best ? key : best;
      }
#pragma unroll
      for (int off = 1; off < 16; off <<= 1) {
        unsigned long long o = shfl_xor_u64(best, off);
        best = o < best ? o : best;
      }
      if (li == 0) {
        const int m = m0 + wm + mi * 16 + lq * 4 + r;
        atomicMin(&keys[m], best);  // tie -> lower idx = first occurrence
      }
    }
  }
}

// ---------- gather + index write (4 rows per block) ----------
__global__ __launch_bounds__(256) void gather2_kernel(const float* __restrict__ embed,
                                                      const unsigned long long* __restrict__ keys,
                                                      float* __restrict__ out) {
  const int row = blockIdx.x * 4 + (threadIdx.x >> 6);
  const int lane = threadIdx.x & 63;
  const unsigned idx = (unsigned)keys[row];
  reinterpret_cast<float4*>(out)[(size_t)row * 64 + lane] =
      reinterpret_cast<const float4*>(embed)[(size_t)idx * 64 + lane];
  if (lane == 0) out[(size_t)M_TOT * K_TOT + row] = (float)idx;
}

// ================= fallback (round-1 fp32 path, known-correct) =================
#define BM 32
#define BN 64
#define KC 32
#define NQ 2
#define NPQ (N_TOT / NQ)
#define SB 72

__global__ __launch_bounds__(256) void esq_kernel(const float* __restrict__ embed,
                                                  float* __restrict__ esq) {
  const int lane = threadIdx.x & 63;
  const int wave = threadIdx.x >> 6;
  const int code = blockIdx.x * 4 + wave;
  float4 v = reinterpret_cast<const float4*>(embed + (size_t)code * K_TOT)[lane];
  float s = v.x * v.x + v.y * v.y + v.z * v.z + v.w * v.w;
#pragma unroll
  for (int off = 32; off > 0; off >>= 1) s += __shfl_xor(s, off, 64);
  if (lane == 0) esq[code] = s;
}

__global__ __launch_bounds__(256, 2) void argmin_kernel(
    const float* __restrict__ x, const float* __restrict__ embed,
    const float* __restrict__ esq, float* __restrict__ pval, int* __restrict__ pidx) {
  __shared__ float A[K_TOT][BM];
  __shared__ float Bs[KC][SB];
  const int tid = threadIdx.x;
  const int tx = tid & 15;
  const int ty = tid >> 4;
  const int q = blockIdx.x & 1;
  const int mb = blockIdx.x >> 1;
  const int m0 = mb * BM;
  const int nq0 = q * NPQ;
#pragma unroll
  for (int it = 0; it < 8; ++it) {
    int idx = it * 256 + tid;
    int row = idx >> 6;
    int k4 = idx & 63;
    float4 v = reinterpret_cast<const float4*>(x + (size_t)(m0 + row) * K_TOT)[k4];
    A[k4 * 4 + 0][row] = v.x; A[k4 * 4 + 1][row] = v.y;
    A[k4 * 4 + 2][row] = v.z; A[k4 * 4 + 3][row] = v.w;
  }
  float minv[2]; int mini[2];
#pragma unroll
  for (int r = 0; r < 2; ++r) { minv[r] = 3.4e38f; mini[r] = 0; }
  for (int ns = 0; ns < NPQ / BN; ++ns) {
    const int n0 = nq0 + ns * BN;
    float acc[2][4];
#pragma unroll
    for (int r = 0; r < 2; ++r)
#pragma unroll
      for (int c = 0; c < 4; ++c) acc[r][c] = 0.0f;
    for (int kc = 0; kc < K_TOT / KC; ++kc) {
      const int k0 = kc * KC;
      __syncthreads();
#pragma unroll
      for (int it = 0; it < 2; ++it) {
        int idx = it * 256 + tid;
        int nl = idx >> 3;
        int k4 = idx & 7;
        float4 v = reinterpret_cast<const float4*>(embed + (size_t)(n0 + nl) * K_TOT + k0)[k4];
        Bs[k4 * 4 + 0][nl] = v.x; Bs[k4 * 4 + 1][nl] = v.y;
        Bs[k4 * 4 + 2][nl] = v.z; Bs[k4 * 4 + 3][nl] = v.w;
      }
      __syncthreads();
#pragma unroll
      for (int kk = 0; kk < KC; ++kk) {
        float2 a = *reinterpret_cast<const float2*>(&A[k0 + kk][ty * 2]);
        float4 b = *reinterpret_cast<const float4*>(&Bs[kk][tx * 4]);
        acc[0][0] += a.x * b.x; acc[0][1] += a.x * b.y;
        acc[0][2] += a.x * b.z; acc[0][3] += a.x * b.w;
        acc[1][0] += a.y * b.x; acc[1][1] += a.y * b.y;
        acc[1][2] += a.y * b.z; acc[1][3] += a.y * b.w;
      }
    }
    float4 es = *reinterpret_cast<const float4*>(&esq[n0 + tx * 4]);
    float e[4] = {es.x, es.y, es.z, es.w};
#pragma unroll
    for (int r = 0; r < 2; ++r)
#pragma unroll
      for (int c = 0; c < 4; ++c) {
        float d = e[c] - 2.0f * acc[r][c];
        int id = n0 + tx * 4 + c;
        if (d < minv[r]) { minv[r] = d; mini[r] = id; }
      }
  }
#pragma unroll
  for (int r = 0; r < 2; ++r) {
    float v = minv[r]; int i = mini[r];
#pragma unroll
    for (int off = 1; off < 16; off <<= 1) {
      float vo = __shfl_xor(v, off, 64);
      int io = __shfl_xor(i, off, 64);
      if (vo < v || (vo == v && io < i)) { v = vo; i = io; }
    }
    if (tx == 0) {
      int row = m0 + ty * 2 + r;
      pval[q * M_TOT + row] = v;
      pidx[q * M_TOT + row] = i;
    }
  }
}

__global__ __launch_bounds__(256) void gather_kernel(
    const float* __restrict__ embed, const float* __restrict__ pval,
    const int* __restrict__ pidx, float* __restrict__ out) {
  const int row = blockIdx.x;
  float bv = pval[row]; int bi = pidx[row];
#pragma unroll
  for (int qq = 1; qq < NQ; ++qq) {
    float v = pval[qq * M_TOT + row];
    int i = pidx[qq * M_TOT + row];
    if (v < bv || (v == bv && i < bi)) { bv = v; bi = i; }
  }
  out[(size_t)row * K_TOT + threadIdx.x] = embed[(size_t)bi * K_TOT + threadIdx.x];
  if (threadIdx.x == 0) out[(size_t)M_TOT * K_TOT + row] = (float)bi;
}

// ================= launch =================
extern "C" void kernel_launch(void* const* d_in, const int* in_sizes, int n_in,
                              void* d_out, int out_size, void* d_ws, size_t ws_size,
                              hipStream_t stream) {
  const float* x = (const float*)d_in[0];
  const float* embed = (const float*)d_in[1];
  float* out = (float*)d_out;
  char* ws = (char*)d_ws;

  const size_t SPLIT_BYTES = (size_t)M_TOT * K_TOT * 2;  // 4 MB per split matrix
  const size_t need = (1u << 20) + 4 * SPLIT_BYTES;      // ~17.8 MB

  if (ws_size >= need) {
    unsigned long long* keys = (unsigned long long*)ws;  // 64 KB
    float* esq = (float*)(ws + 65536);                   // 32 KB
    unsigned short* S[4];
    for (int i = 0; i < 4; ++i) S[i] = (unsigned short*)(ws + (1u << 20) + i * SPLIT_BYTES);
    prep_kernel<<<4096, 256, 0, stream>>>(x, embed, S[0], S[1], S[2], S[3], esq, keys);
    mfma_argmin_kernel<<<4096, 256, 0, stream>>>(S[0], S[1], S[2], S[3], esq, keys);
    gather2_kernel<<<2048, 256, 0, stream>>>(embed, keys, out);
  } else {
    float* esq = (float*)ws;
    float* pval = (float*)(ws + 32768);
    int* pidx = (int*)(ws + 32768 + NQ * 32768);
    esq_kernel<<<2048, 256, 0, stream>>>(embed, esq);
    argmin_kernel<<<512, 256, 0, stream>>>(x, embed, esq, pval, pidx);
    gather_kernel<<<M_TOT, 256, 0, stream>>>(embed, pval, pidx, out);
  }
}